// Round 1
// baseline (14754.109 us; speedup 1.0000x reference)
//
#include <hip/hip_runtime.h>

#define T_STEPS 512
#define BATCH   64
#define IN_SZ   32
#define AD      32
#define INNER   256
#define PROJ    224
#define HID     512

typedef __attribute__((ext_vector_type(8))) short short8;
typedef __attribute__((ext_vector_type(4))) float f32x4;
typedef __attribute__((ext_vector_type(4))) int   i32x4;

static __device__ __forceinline__ unsigned short f2bf(float f) {
  unsigned int u = __float_as_uint(f);
  u += 0x7FFFu + ((u >> 16) & 1u);
  return (unsigned short)(u >> 16);
}
static __device__ __forceinline__ float sigmoidf_(float x) { return 1.f / (1.f + __expf(-x)); }
static __device__ __forceinline__ float tanhf_(float x) {
  float e = __expf(-2.f * fabsf(x));
  float r = (1.f - e) / (1.f + e);
  return x < 0.f ? -r : r;
}

// ---------------- kernel A: x = [relu(in_w@state+in_b) | emb[idx]] as bf16, layout [t][b][256]
__global__ __launch_bounds__(256) void k_prep(
    const float* __restrict__ ws_in, const int* __restrict__ act_idx,
    const float* __restrict__ emb, const float* __restrict__ in_w,
    const float* __restrict__ in_b, unsigned short* __restrict__ x_bf)
{
  int bid = blockIdx.x;            // t*64 + b
  int t = bid >> 6, b = bid & 63;
  __shared__ float st[IN_SZ];
  int tid = threadIdx.x;
  if (tid < IN_SZ) st[tid] = ws_in[(size_t)(b * T_STEPS + t) * IN_SZ + tid];
  __syncthreads();
  unsigned short* xrow = x_bf + (size_t)(t * BATCH + b) * INNER;
  if (tid < PROJ) {
    const float* wrow = in_w + tid * IN_SZ;
    float acc = in_b[tid];
#pragma unroll
    for (int k = 0; k < IN_SZ; ++k) acc += wrow[k] * st[k];
    xrow[tid] = f2bf(fmaxf(acc, 0.f));
  } else {
    int j = tid - PROJ;
    int a = act_idx[b * T_STEPS + t];
    xrow[tid] = f2bf(emb[a * AD + j]);
  }
}

// ---------------- helpers for persistent LSTM kernel ----------------
static __device__ __forceinline__ short8 bfrag_load(const float* __restrict__ w, int stride, int row, int k0) {
  const float* p = w + (size_t)row * stride + k0;
  f32x4 a = *reinterpret_cast<const f32x4*>(p);
  f32x4 b = *reinterpret_cast<const f32x4*>(p + 4);
  short8 r;
  r[0] = (short)f2bf(a[0]); r[1] = (short)f2bf(a[1]); r[2] = (short)f2bf(a[2]); r[3] = (short)f2bf(a[3]);
  r[4] = (short)f2bf(b[0]); r[5] = (short)f2bf(b[1]); r[6] = (short)f2bf(b[2]); r[7] = (short)f2bf(b[3]);
  return r;
}

// copy 16 rows x RB bytes (contiguous global) into LDS with XOR swizzle (bank-conflict-free frag reads)
template<int RB>
static __device__ __forceinline__ void stage(unsigned char* lds, const unsigned char* g, int tid) {
  constexpr int UPR = RB >> 4;
  constexpr int UNITS = 16 * UPR;
#pragma unroll
  for (int u = tid; u < UNITS; u += 256) {
    int row = u / UPR;
    int c16 = u % UPR;
    i32x4 v = *reinterpret_cast<const i32x4*>(g + (size_t)u * 16);
    *reinterpret_cast<i32x4*>(lds + row * RB + ((c16 * 16) ^ ((row & 7) << 4))) = v;
  }
}

// A-fragment for mfma_f32_16x16x32_bf16: lane l supplies A[row=l&15][k = chunk*32 + (l>>4)*8 + j]
template<int RB>
static __device__ __forceinline__ short8 afrag(const unsigned char* lds, int lane, int chunk) {
  int row = lane & 15;
  int cb = chunk * 64 + ((lane >> 4) << 4);
  return *reinterpret_cast<const short8*>(lds + row * RB + (cb ^ ((row & 7) << 4)));
}

static __device__ __forceinline__ void waitcnt_ge(unsigned int* p, unsigned int tgt) {
  while (__hip_atomic_load(p, __ATOMIC_ACQUIRE, __HIP_MEMORY_SCOPE_AGENT) < tgt)
    __builtin_amdgcn_s_sleep(1);
}

// ---------------- persistent 2-layer LSTM ----------------
// 256 blocks: xg = blockIdx&7 -> (layer = xg>=4, batch-group bg = xg&3); blk = blockIdx>>3 owns hidden [blk*16, blk*16+16).
// Weights live in VGPRs as pre-converted bf16 B-fragments (K split over 4 waves). c-state in registers.
// h exchanged via global slots; sync = per-group monotonic counters (device-scope atomics).
template<int L>
static __device__ void lstm_body(
    const unsigned short* __restrict__ x_bf,
    const float* __restrict__ wih, const float* __restrict__ whh,
    const float* __restrict__ bih, const float* __restrict__ bhh,
    unsigned short* __restrict__ h0buf, unsigned short* __restrict__ h1buf,
    float* __restrict__ h1fin,
    unsigned int* cnt0, unsigned int* cnt1,
    int bg, int blk, unsigned char* st0, unsigned char* st1, float* spart)
{
  constexpr int KX  = (L == 0) ? INNER : HID;  // K of input-side matvec
  constexpr int KI  = KX / 128;                // k-chunks per wave quarter (2 or 4)
  constexpr int RBX = KX * 2;                  // LDS row bytes for input staging

  const int tid  = threadIdx.x;
  const int lane = tid & 63;
  const int wv   = tid >> 6;
  const int hid0 = blk << 4;
  const int q    = lane >> 4;
  const int ln   = lane & 15;

  unsigned int* myc  = (L == 0) ? (cnt0 + bg * 32) : (cnt1 + bg * 32);
  unsigned int* othc = (L == 0) ? (cnt1 + bg * 32) : (cnt0 + bg * 32);

  const int m = tid >> 4;   // batch-in-group
  const int n = tid & 15;   // hid offset

  float bias[4];
#pragma unroll
  for (int g = 0; g < 4; ++g)
    bias[g] = bih[g * HID + hid0 + n] + bhh[g * HID + hid0 + n];

  // -------- weight fragments resident in VGPRs (one-time load, f32 -> bf16) --------
  short8 fih[4 * KI];
#pragma unroll
  for (int g = 0; g < 4; ++g)
#pragma unroll
    for (int kk = 0; kk < KI; ++kk)
      fih[g * KI + kk] = bfrag_load(wih, KX, g * HID + hid0 + ln, wv * (KX / 4) + kk * 32 + q * 8);
  short8 fhh[16];
#pragma unroll
  for (int g = 0; g < 4; ++g)
#pragma unroll
    for (int kk = 0; kk < 4; ++kk)
      fhh[g * 4 + kk] = bfrag_load(whh, HID, g * HID + hid0 + ln, wv * 128 + kk * 32 + q * 8);

  float c_state = 0.f;

  for (int t = 0; t < T_STEPS; ++t) {
    if (tid == 0) {
      if (L == 0) {
        if (t > 0)  waitcnt_ge(myc, 32u * (unsigned)t);         // own group step t-1 done
        if (t >= 4) waitcnt_ge(othc, 32u * (unsigned)(t - 3));  // slot reuse guard vs layer 1
      } else {
        waitcnt_ge(othc, 32u * (unsigned)(t + 1));              // h0[t] published
        if (t > 0) waitcnt_ge(myc, 32u * (unsigned)t);          // own group step t-1 done
      }
    }
    __syncthreads();

    const unsigned short* xin = (L == 0)
        ? x_bf + (size_t)(t * BATCH + bg * 16) * INNER
        : h0buf + (size_t)(((t & 3) * 4 + bg) * 16) * HID;
    stage<RBX>(st0, (const unsigned char*)xin, tid);
    if (t > 0) {
      const unsigned short* hin = (L == 0)
          ? h0buf + (size_t)((((t - 1) & 3) * 4 + bg) * 16) * HID
          : h1buf + (size_t)((((t - 1) & 1) * 4 + bg) * 16) * HID;
      stage<1024>(st1, (const unsigned char*)hin, tid);
    }
    __syncthreads();

    f32x4 acc[4];
#pragma unroll
    for (int g = 0; g < 4; ++g) acc[g] = (f32x4){0.f, 0.f, 0.f, 0.f};

#pragma unroll
    for (int kk = 0; kk < KI; ++kk) {
      short8 a = afrag<RBX>(st0, lane, wv * KI + kk);
#pragma unroll
      for (int g = 0; g < 4; ++g)
        acc[g] = __builtin_amdgcn_mfma_f32_16x16x32_bf16(a, fih[g * KI + kk], acc[g], 0, 0, 0);
    }
    if (t > 0) {
#pragma unroll
      for (int kk = 0; kk < 4; ++kk) {
        short8 a = afrag<1024>(st1, lane, wv * 4 + kk);
#pragma unroll
        for (int g = 0; g < 4; ++g)
          acc[g] = __builtin_amdgcn_mfma_f32_16x16x32_bf16(a, fhh[g * 4 + kk], acc[g], 0, 0, 0);
      }
    }

    // K-split partials -> LDS  (D layout: row = (lane>>4)*4+r = batch, col = lane&15 = hid)
#pragma unroll
    for (int g = 0; g < 4; ++g)
#pragma unroll
      for (int r = 0; r < 4; ++r)
        spart[((wv * 4 + g) * 16 + (q * 4 + r)) * 16 + ln] = acc[g][r];
    __syncthreads();

    float gate[4];
#pragma unroll
    for (int g = 0; g < 4; ++g) {
      float s = bias[g];
#pragma unroll
      for (int w2 = 0; w2 < 4; ++w2) s += spart[((w2 * 4 + g) * 16 + m) * 16 + n];
      gate[g] = s;
    }
    float gi = sigmoidf_(gate[0]);
    float gf = sigmoidf_(gate[1]);
    float gc = tanhf_(gate[2]);
    float go = sigmoidf_(gate[3]);
    c_state = gf * c_state + gi * gc;
    float h = go * tanhf_(c_state);

    unsigned short hb = f2bf(h);
    if (L == 0) {
      h0buf[(size_t)(((t & 3) * 4 + bg) * 16 + m) * HID + hid0 + n] = hb;
    } else {
      h1buf[(size_t)(((t & 1) * 4 + bg) * 16 + m) * HID + hid0 + n] = hb;
      if (t == T_STEPS - 1) h1fin[(size_t)(bg * 16 + m) * HID + hid0 + n] = h;
    }
    __threadfence();
    __syncthreads();
    if (tid == 0)
      __hip_atomic_fetch_add(myc, 1u, __ATOMIC_RELEASE, __HIP_MEMORY_SCOPE_AGENT);
  }
}

__global__ __launch_bounds__(256, 1) void k_lstm(
    const unsigned short* __restrict__ x_bf,
    const float* __restrict__ w_ih0, const float* __restrict__ w_hh0,
    const float* __restrict__ b_ih0, const float* __restrict__ b_hh0,
    const float* __restrict__ w_ih1, const float* __restrict__ w_hh1,
    const float* __restrict__ b_ih1, const float* __restrict__ b_hh1,
    unsigned short* h0buf, unsigned short* h1buf, float* h1fin,
    unsigned int* cnt0, unsigned int* cnt1)
{
  __shared__ __align__(16) unsigned char st0[16 * 1024];
  __shared__ __align__(16) unsigned char st1[16 * 1024];
  __shared__ float spart[4 * 4 * 16 * 16];
  const int xg  = blockIdx.x & 7;
  const int blk = blockIdx.x >> 3;
  const int bg  = xg & 3;
  if (xg < 4)
    lstm_body<0>(x_bf, w_ih0, w_hh0, b_ih0, b_hh0, h0buf, h1buf, h1fin, cnt0, cnt1, bg, blk, st0, st1, spart);
  else
    lstm_body<1>(x_bf, w_ih1, w_hh1, b_ih1, b_hh1, h0buf, h1buf, h1fin, cnt0, cnt1, bg, blk, st0, st1, spart);
}

// ---------------- output head on final h1 (fp32) ----------------
__global__ __launch_bounds__(256) void k_head(
    const float* __restrict__ h1, const float* __restrict__ w1, const float* __restrict__ b1,
    const float* __restrict__ w2, const float* __restrict__ b2, float* __restrict__ out)
{
  int b = blockIdx.x, tid = threadIdx.x;
  __shared__ float sh[HID];
  __shared__ float sm[2 * HID];
  for (int k = tid; k < HID; k += 256) sh[k] = h1[(size_t)b * HID + k];
  __syncthreads();
#pragma unroll
  for (int r0 = 0; r0 < 4; ++r0) {
    int row = r0 * 256 + tid;
    const f32x4* wr = reinterpret_cast<const f32x4*>(w1 + (size_t)row * HID);
    float s = 0.f;
#pragma unroll 4
    for (int k = 0; k < HID / 4; ++k) {
      f32x4 v = wr[k];
      s += v[0] * sh[k * 4] + v[1] * sh[k * 4 + 1] + v[2] * sh[k * 4 + 2] + v[3] * sh[k * 4 + 3];
    }
    sm[row] = fmaxf(b1[row] + s, 0.f);
  }
  __syncthreads();
  if (tid < 32) {
    const f32x4* wr = reinterpret_cast<const f32x4*>(w2 + (size_t)tid * 2 * HID);
    float s = b2[tid];
#pragma unroll 4
    for (int k = 0; k < 2 * HID / 4; ++k) {
      f32x4 v = wr[k];
      s += v[0] * sm[k * 4] + v[1] * sm[k * 4 + 1] + v[2] * sm[k * 4 + 2] + v[3] * sm[k * 4 + 3];
    }
    if (tid >= 24) s = sigmoidf_(s);   // CAT_FLAGS[24:]
    out[b * 32 + tid] = s;
  }
}

extern "C" void kernel_launch(void* const* d_in, const int* in_sizes, int n_in,
                              void* d_out, int out_size, void* d_ws, size_t ws_size,
                              hipStream_t stream) {
  const float* ws_in  = (const float*)d_in[0];
  const int*   aidx   = (const int*)d_in[1];
  const float* emb    = (const float*)d_in[2];
  const float* in_w   = (const float*)d_in[3];
  const float* in_b   = (const float*)d_in[4];
  const float* w_ih0  = (const float*)d_in[5];
  const float* w_hh0  = (const float*)d_in[6];
  const float* b_ih0  = (const float*)d_in[7];
  const float* b_hh0  = (const float*)d_in[8];
  const float* w_ih1  = (const float*)d_in[9];
  const float* w_hh1  = (const float*)d_in[10];
  const float* b_ih1  = (const float*)d_in[11];
  const float* b_hh1  = (const float*)d_in[12];
  const float* out_w1 = (const float*)d_in[13];
  const float* out_b1 = (const float*)d_in[14];
  const float* out_w2 = (const float*)d_in[15];
  const float* out_b2 = (const float*)d_in[16];

  unsigned char* ws = (unsigned char*)d_ws;
  const size_t X_OFF  = 0;                 // 512*64*256*2    = 16,777,216
  const size_t H0_OFF = 16777216;          // 4*4*16*512*2    = 262,144
  const size_t H1_OFF = H0_OFF + 262144;   // 2*4*16*512*2    = 131,072
  const size_t HF_OFF = H1_OFF + 131072;   // 64*512*4        = 131,072
  const size_t CT_OFF = HF_OFF + 131072;   // counters        = 2,048
  unsigned short* x_bf  = (unsigned short*)(ws + X_OFF);
  unsigned short* h0buf = (unsigned short*)(ws + H0_OFF);
  unsigned short* h1buf = (unsigned short*)(ws + H1_OFF);
  float*          h1fin = (float*)(ws + HF_OFF);
  unsigned int*   cnts  = (unsigned int*)(ws + CT_OFF);

  hipMemsetAsync(ws + CT_OFF, 0, 2048, stream);
  k_prep<<<dim3(T_STEPS * BATCH), dim3(256), 0, stream>>>(ws_in, aidx, emb, in_w, in_b, x_bf);
  k_lstm<<<dim3(256), dim3(256), 0, stream>>>(x_bf, w_ih0, w_hh0, b_ih0, b_hh0,
                                              w_ih1, w_hh1, b_ih1, b_hh1,
                                              h0buf, h1buf, h1fin, cnts, cnts + 256);
  k_head<<<dim3(BATCH), dim3(256), 0, stream>>>(h1fin, out_w1, out_b1, out_w2, out_b2, (float*)d_out);
}

// Round 2
// 2218.075 us; speedup vs baseline: 6.6518x; 6.6518x over previous
//
#include <hip/hip_runtime.h>

#define T_STEPS 512
#define BATCH   64
#define IN_SZ   32
#define AD      32
#define INNER   256
#define PROJ    224
#define HID     512

typedef __attribute__((ext_vector_type(8))) short short8;
typedef __attribute__((ext_vector_type(4))) float f32x4;

static __device__ __forceinline__ unsigned short f2bf(float f) {
  unsigned int u = __float_as_uint(f);
  u += 0x7FFFu + ((u >> 16) & 1u);
  return (unsigned short)(u >> 16);
}
static __device__ __forceinline__ float sigmoidf_(float x) { return 1.f / (1.f + __expf(-x)); }
static __device__ __forceinline__ float tanhf_(float x) {
  float e = __expf(-2.f * fabsf(x));
  float r = (1.f - e) / (1.f + e);
  return x < 0.f ? -r : r;
}

// ---------------- kernel A: x = [relu(in_w@state+in_b) | emb[idx]] bf16, [t][b][256]
__global__ __launch_bounds__(256) void k_prep(
    const float* __restrict__ ws_in, const int* __restrict__ act_idx,
    const float* __restrict__ emb, const float* __restrict__ in_w,
    const float* __restrict__ in_b, unsigned short* __restrict__ x_bf)
{
  int t = blockIdx.x;
  int tid = threadIdx.x;
  __shared__ float st[BATCH * IN_SZ];
  __shared__ int ai[BATCH];
  for (int i = tid; i < BATCH * IN_SZ; i += 256) {
    int b = i >> 5, k = i & 31;
    st[i] = ws_in[((size_t)b * T_STEPS + t) * IN_SZ + k];
  }
  if (tid < BATCH) ai[tid] = act_idx[tid * T_STEPS + t];
  __syncthreads();
  if (tid < PROJ) {
    float w[IN_SZ];
    const float* wrow = in_w + tid * IN_SZ;
#pragma unroll
    for (int k = 0; k < IN_SZ; ++k) w[k] = wrow[k];
    float bb = in_b[tid];
    for (int b = 0; b < BATCH; ++b) {
      float acc = bb;
      const float* sb = st + b * IN_SZ;
#pragma unroll
      for (int k = 0; k < IN_SZ; ++k) acc += w[k] * sb[k];
      x_bf[((size_t)t * BATCH + b) * INNER + tid] = f2bf(fmaxf(acc, 0.f));
    }
  } else {
    int j = tid - PROJ;
    for (int b = 0; b < BATCH; ++b)
      x_bf[((size_t)t * BATCH + b) * INNER + tid] = f2bf(emb[ai[b] * AD + j]);
  }
}

// ---------------- helpers ----------------
static __device__ __forceinline__ short8 bfrag_load(const float* __restrict__ w, int stride, int row, int k0) {
  const float* p = w + (size_t)row * stride + k0;
  f32x4 a = *reinterpret_cast<const f32x4*>(p);
  f32x4 b = *reinterpret_cast<const f32x4*>(p + 4);
  short8 r;
  r[0] = (short)f2bf(a[0]); r[1] = (short)f2bf(a[1]); r[2] = (short)f2bf(a[2]); r[3] = (short)f2bf(a[3]);
  r[4] = (short)f2bf(b[0]); r[5] = (short)f2bf(b[1]); r[6] = (short)f2bf(b[2]); r[7] = (short)f2bf(b[3]);
  return r;
}

union U16B { unsigned long long u[2]; short8 s; };

// 16B A-fragment straight from LLC (relaxed agent atomics -> sc0 sc1, no fences)
static __device__ __forceinline__ short8 llc_frag(const unsigned long long* p) {
  U16B r;
  r.u[0] = __hip_atomic_load(p,     __ATOMIC_RELAXED, __HIP_MEMORY_SCOPE_AGENT);
  r.u[1] = __hip_atomic_load(p + 1, __ATOMIC_RELAXED, __HIP_MEMORY_SCOPE_AGENT);
  return r.s;
}

// wave-parallel poll of 32 per-block flags; exit when all >= tgt
static __device__ __forceinline__ void poll_ge(const unsigned int* f, unsigned int tgt) {
  const unsigned int* p = f + (threadIdx.x & 31);
  while (1) {
    unsigned int v = __hip_atomic_load(p, __ATOMIC_RELAXED, __HIP_MEMORY_SCOPE_AGENT);
    if (__all((int)(v >= tgt))) break;
    __builtin_amdgcn_s_sleep(1);
  }
  asm volatile("" ::: "memory");  // no data load hoisted above the poll
}

// ---------------- persistent 2-layer LSTM ----------------
// 256 blocks: xg=blockIdx&7 -> layer=xg>=4, bg=xg&3; blk=blockIdx>>3 owns hid [blk*16,blk*16+16).
// Weights in VGPRs (bf16 B-frags, K split over 4 waves). No LDS staging: A-frags loaded
// directly (x_bf cached; h via LLC-coherent relaxed atomics). Sync: 32 flag words/group.
template<int L>
static __device__ void lstm_body(
    const unsigned short* __restrict__ x_bf,
    const float* __restrict__ wih, const float* __restrict__ whh,
    const float* __restrict__ bih, const float* __restrict__ bhh,
    unsigned short* __restrict__ h0buf, unsigned short* __restrict__ h1buf,
    float* __restrict__ h1fin, unsigned int* __restrict__ flags,
    int bg, int blk, float* __restrict__ spart)
{
  constexpr int KX = (L == 0) ? INNER : HID;
  constexpr int KI = KX / 128;

  const int tid  = threadIdx.x;
  const int lane = tid & 63;
  const int wv   = tid >> 6;
  const int q    = lane >> 4;
  const int ln   = lane & 15;
  const int hid0 = blk << 4;
  const int m    = tid >> 4;
  const int n    = tid & 15;

  unsigned int* fown = flags + (L * 4 + bg) * 32;
  unsigned int* foth = flags + ((1 - L) * 4 + bg) * 32;

  float bias[4];
#pragma unroll
  for (int g = 0; g < 4; ++g)
    bias[g] = bih[g * HID + hid0 + n] + bhh[g * HID + hid0 + n];

  short8 fih[4 * KI];
#pragma unroll
  for (int g = 0; g < 4; ++g)
#pragma unroll
    for (int kk = 0; kk < KI; ++kk)
      fih[g * KI + kk] = bfrag_load(wih, KX, g * HID + hid0 + ln, (wv * KI + kk) * 32 + q * 8);
  short8 fhh[16];
#pragma unroll
  for (int g = 0; g < 4; ++g)
#pragma unroll
    for (int kk = 0; kk < 4; ++kk)
      fhh[g * 4 + kk] = bfrag_load(whh, HID, g * HID + hid0 + ln, (wv * 4 + kk) * 32 + q * 8);

  float c_state = 0.f;

  for (int t = 0; t < T_STEPS; ++t) {
    f32x4 acc[4];
#pragma unroll
    for (int g = 0; g < 4; ++g) acc[g] = (f32x4){0.f, 0.f, 0.f, 0.f};

    if constexpr (L == 0) {
      // x-side first: static data, hides under the wait
      const unsigned short* xr = x_bf + ((size_t)t * BATCH + bg * 16 + ln) * INNER;
#pragma unroll
      for (int kk = 0; kk < KI; ++kk) {
        short8 a = *reinterpret_cast<const short8*>(xr + (wv * KI + kk) * 32 + q * 8);
#pragma unroll
        for (int g = 0; g < 4; ++g)
          acc[g] = __builtin_amdgcn_mfma_f32_16x16x32_bf16(a, fih[g * KI + kk], acc[g], 0, 0, 0);
      }
      if (t > 0) {
        poll_ge(fown, (unsigned)t);                    // own group step t-1 done
        if (t >= 4) poll_ge(foth, (unsigned)(t - 3));  // slot-reuse guard vs layer 1
        const unsigned long long* hr = reinterpret_cast<const unsigned long long*>(h0buf)
            + ((size_t)((((t - 1) & 3) * 4 + bg) * 16 + ln)) * (HID / 4);
#pragma unroll
        for (int kk = 0; kk < 4; ++kk) {
          short8 a = llc_frag(hr + wv * 32 + kk * 8 + q * 2);
#pragma unroll
          for (int g = 0; g < 4; ++g)
            acc[g] = __builtin_amdgcn_mfma_f32_16x16x32_bf16(a, fhh[g * 4 + kk], acc[g], 0, 0, 0);
        }
      }
    } else {
      if (t > 0) {
        poll_ge(fown, (unsigned)t);                    // h1[t-1] ready (also h1 slot guard)
        const unsigned long long* hr = reinterpret_cast<const unsigned long long*>(h1buf)
            + ((size_t)((((t - 1) & 1) * 4 + bg) * 16 + ln)) * (HID / 4);
#pragma unroll
        for (int kk = 0; kk < 4; ++kk) {
          short8 a = llc_frag(hr + wv * 32 + kk * 8 + q * 2);
#pragma unroll
          for (int g = 0; g < 4; ++g)
            acc[g] = __builtin_amdgcn_mfma_f32_16x16x32_bf16(a, fhh[g * 4 + kk], acc[g], 0, 0, 0);
        }
      }
      poll_ge(foth, (unsigned)(t + 1));                // h0[t] published by layer 0
      const unsigned long long* xr = reinterpret_cast<const unsigned long long*>(h0buf)
          + ((size_t)(((t & 3) * 4 + bg) * 16 + ln)) * (HID / 4);
#pragma unroll
      for (int kk = 0; kk < 4; ++kk) {
        short8 a = llc_frag(xr + wv * 32 + kk * 8 + q * 2);
#pragma unroll
        for (int g = 0; g < 4; ++g)
          acc[g] = __builtin_amdgcn_mfma_f32_16x16x32_bf16(a, fih[g * 4 + kk], acc[g], 0, 0, 0);
      }
    }

    // K-split partials -> LDS (conflict-free: consecutive lanes hit consecutive dwords)
#pragma unroll
    for (int g = 0; g < 4; ++g)
#pragma unroll
      for (int r = 0; r < 4; ++r)
        spart[((wv * 4 + g) * 16 + (q * 4 + r)) * 16 + ln] = acc[g][r];
    __syncthreads();

    float gate[4];
#pragma unroll
    for (int g = 0; g < 4; ++g) {
      float s = bias[g];
#pragma unroll
      for (int w2 = 0; w2 < 4; ++w2) s += spart[((w2 * 4 + g) * 16 + m) * 16 + n];
      gate[g] = s;
    }
    float gi = sigmoidf_(gate[0]);
    float gf = sigmoidf_(gate[1]);
    float gc = tanhf_(gate[2]);
    float go = sigmoidf_(gate[3]);
    c_state = gf * c_state + gi * gc;
    float h = go * tanhf_(c_state);

    // pack pairs (n even | n+1) into u32, store LLC-coherent
    float hp = __shfl_xor(h, 1);
    unsigned int wword = (unsigned)f2bf(h) | ((unsigned)f2bf(hp) << 16);
    if constexpr (L == 0) {
      if (!(n & 1)) {
        unsigned int* dst = reinterpret_cast<unsigned int*>(h0buf)
            + (((size_t)(((t & 3) * 4 + bg) * 16 + m)) * HID + hid0 + n) / 2;
        __hip_atomic_store(dst, wword, __ATOMIC_RELAXED, __HIP_MEMORY_SCOPE_AGENT);
      }
    } else {
      if (!(n & 1)) {
        unsigned int* dst = reinterpret_cast<unsigned int*>(h1buf)
            + (((size_t)(((t & 1) * 4 + bg) * 16 + m)) * HID + hid0 + n) / 2;
        __hip_atomic_store(dst, wword, __ATOMIC_RELAXED, __HIP_MEMORY_SCOPE_AGENT);
      }
      if (t == T_STEPS - 1)
        h1fin[(size_t)(bg * 16 + m) * HID + hid0 + n] = h;  // plain store; next-kernel visibility
    }

    // drain this wave's stores, barrier (emits vmcnt(0) for all waves), publish flag
    asm volatile("s_waitcnt vmcnt(0)" ::: "memory");
    __syncthreads();
    if (tid == 0)
      __hip_atomic_store(fown + blk, (unsigned)(t + 1), __ATOMIC_RELAXED, __HIP_MEMORY_SCOPE_AGENT);
  }
}

__global__ __launch_bounds__(256, 1) void k_lstm(
    const unsigned short* __restrict__ x_bf,
    const float* __restrict__ w_ih0, const float* __restrict__ w_hh0,
    const float* __restrict__ b_ih0, const float* __restrict__ b_hh0,
    const float* __restrict__ w_ih1, const float* __restrict__ w_hh1,
    const float* __restrict__ b_ih1, const float* __restrict__ b_hh1,
    unsigned short* h0buf, unsigned short* h1buf, float* h1fin,
    unsigned int* flags)
{
  __shared__ float spart[4 * 4 * 16 * 16];
  const int xg  = blockIdx.x & 7;
  const int blk = blockIdx.x >> 3;
  const int bg  = xg & 3;
  if (xg < 4)
    lstm_body<0>(x_bf, w_ih0, w_hh0, b_ih0, b_hh0, h0buf, h1buf, h1fin, flags, bg, blk, spart);
  else
    lstm_body<1>(x_bf, w_ih1, w_hh1, b_ih1, b_hh1, h0buf, h1buf, h1fin, flags, bg, blk, spart);
}

// ---------------- output head on final h1 (fp32) ----------------
__global__ __launch_bounds__(256) void k_head(
    const float* __restrict__ h1, const float* __restrict__ w1, const float* __restrict__ b1,
    const float* __restrict__ w2, const float* __restrict__ b2, float* __restrict__ out)
{
  int b = blockIdx.x, tid = threadIdx.x;
  __shared__ float sh[HID];
  __shared__ float sm[2 * HID];
  for (int k = tid; k < HID; k += 256) sh[k] = h1[(size_t)b * HID + k];
  __syncthreads();
#pragma unroll
  for (int r0 = 0; r0 < 4; ++r0) {
    int row = r0 * 256 + tid;
    const f32x4* wr = reinterpret_cast<const f32x4*>(w1 + (size_t)row * HID);
    float s = 0.f;
#pragma unroll 4
    for (int k = 0; k < HID / 4; ++k) {
      f32x4 v = wr[k];
      s += v[0] * sh[k * 4] + v[1] * sh[k * 4 + 1] + v[2] * sh[k * 4 + 2] + v[3] * sh[k * 4 + 3];
    }
    sm[row] = fmaxf(b1[row] + s, 0.f);
  }
  __syncthreads();
  if (tid < 32) {
    const f32x4* wr = reinterpret_cast<const f32x4*>(w2 + (size_t)tid * 2 * HID);
    float s = b2[tid];
#pragma unroll 4
    for (int k = 0; k < 2 * HID / 4; ++k) {
      f32x4 v = wr[k];
      s += v[0] * sm[k * 4] + v[1] * sm[k * 4 + 1] + v[2] * sm[k * 4 + 2] + v[3] * sm[k * 4 + 3];
    }
    if (tid >= 24) s = sigmoidf_(s);   // CAT_FLAGS[24:]
    out[b * 32 + tid] = s;
  }
}

extern "C" void kernel_launch(void* const* d_in, const int* in_sizes, int n_in,
                              void* d_out, int out_size, void* d_ws, size_t ws_size,
                              hipStream_t stream) {
  const float* ws_in  = (const float*)d_in[0];
  const int*   aidx   = (const int*)d_in[1];
  const float* emb    = (const float*)d_in[2];
  const float* in_w   = (const float*)d_in[3];
  const float* in_b   = (const float*)d_in[4];
  const float* w_ih0  = (const float*)d_in[5];
  const float* w_hh0  = (const float*)d_in[6];
  const float* b_ih0  = (const float*)d_in[7];
  const float* b_hh0  = (const float*)d_in[8];
  const float* w_ih1  = (const float*)d_in[9];
  const float* w_hh1  = (const float*)d_in[10];
  const float* b_ih1  = (const float*)d_in[11];
  const float* b_hh1  = (const float*)d_in[12];
  const float* out_w1 = (const float*)d_in[13];
  const float* out_b1 = (const float*)d_in[14];
  const float* out_w2 = (const float*)d_in[15];
  const float* out_b2 = (const float*)d_in[16];

  unsigned char* ws = (unsigned char*)d_ws;
  const size_t X_OFF  = 0;                 // 512*64*256*2 = 16,777,216
  const size_t H0_OFF = 16777216;          // 4*4*16*512*2 = 262,144
  const size_t H1_OFF = H0_OFF + 262144;   // 2*4*16*512*2 = 131,072
  const size_t HF_OFF = H1_OFF + 131072;   // 64*512*4     = 131,072
  const size_t FL_OFF = HF_OFF + 131072;   // flags        = 2,048
  unsigned short* x_bf  = (unsigned short*)(ws + X_OFF);
  unsigned short* h0buf = (unsigned short*)(ws + H0_OFF);
  unsigned short* h1buf = (unsigned short*)(ws + H1_OFF);
  float*          h1fin = (float*)(ws + HF_OFF);
  unsigned int*   flags = (unsigned int*)(ws + FL_OFF);

  hipMemsetAsync(ws + FL_OFF, 0, 2048, stream);
  k_prep<<<dim3(T_STEPS), dim3(256), 0, stream>>>(ws_in, aidx, emb, in_w, in_b, x_bf);
  k_lstm<<<dim3(256), dim3(256), 0, stream>>>(x_bf, w_ih0, w_hh0, b_ih0, b_hh0,
                                              w_ih1, w_hh1, b_ih1, b_hh1,
                                              h0buf, h1buf, h1fin, flags);
  k_head<<<dim3(BATCH), dim3(256), 0, stream>>>(h1fin, out_w1, out_b1, out_w2, out_b2, (float*)d_out);
}